// Round 5
// baseline (209.697 us; speedup 1.0000x reference)
//
#include <hip/hip_runtime.h>
#include <math.h>

#define DIMH 256        // D
#define NB   32         // batch
#define E_TOT 43234
#define TE   64         // entities per block
#define DK   32         // d-chunk staged in LDS
#define DQ   128        // d-range per block (d-split by 2)
#define NC   (DQ / DK)  // chunks per block = 4
// reference: phase = rel / (REL_RANGE/PI); REL_RANGE/PI = 0.03125/PI
#define PHASE_DIV 0.009947183943243459f

typedef float v2f __attribute__((ext_vector_type(2)));
typedef float v4f __attribute__((ext_vector_type(4)));

// Kernel 0: out = MARGIN everywhere; dist halves subtract via atomics.
__global__ __launch_bounds__(256) void init_kernel(float* __restrict__ out) {
    int i = blockIdx.x * 256 + threadIdx.x;
    if (i < (NB * E_TOT) / 4) {
        float4 v = make_float4(6.0f, 6.0f, 6.0f, 6.0f);
        reinterpret_cast<float4*>(out)[i] = v;
    }
}

// Kernel 1: rotate head by relation phase (fp32 sincosf).
__global__ void rot_kernel(const float* __restrict__ head,
                           const float* __restrict__ rel,
                           float* __restrict__ rot) {
    int i = blockIdx.x * blockDim.x + threadIdx.x;   // 0..8191
    int b = i >> 8;
    int d = i & 255;
    float re_h = head[b * 2 * DIMH + d];
    float im_h = head[b * 2 * DIMH + DIMH + d];
    float ph = rel[b * DIMH + d] / PHASE_DIV;
    float s, c;
    sincosf(ph, &s, &c);
    rot[b * DIMH + d]             = re_h * c - im_h * s;   // re_rot
    rot[NB * DIMH + b * DIMH + d] = re_h * s + im_h * c;   // im_rot
}

__device__ __forceinline__ v2f sqrt2(v2f s) {
    v2f r;
    r.x = __builtin_amdgcn_sqrtf(s.x);
    r.y = __builtin_amdgcn_sqrtf(s.y);
    return r;
}

// Kernel 2: block = 64-entity tile x 128-d half, all 32 batches.
// LDS element = float4 (re_d, re_d+1, im_d, im_d+1); row stride 17 float4 ->
// b128 reads conflict-free per 8-lane phase (verified ~0.6 extra cyc/read R4).
// LDS = (64+32)*17*16 = 26.1 KB -> 6 blocks/CU = 24 waves/CU (2x R4 pool).
// Register prefetch: next chunk's global loads issued before compute.
// Per-thread register tile: 4 batch x 2 entity.
__global__ __launch_bounds__(256, 6) void dist_kernel(const float* __restrict__ ent,
                                                      const float* __restrict__ rot,
                                                      float* __restrict__ out) {
    __shared__ v4f s_e[TE][DK / 2 + 1];   // 64 x 17 float4 = 17.4 KB
    __shared__ v4f s_r[NB][DK / 2 + 1];   // 32 x 17 float4 =  8.7 KB

    const int tid   = threadIdx.x;
    const int etile = blockIdx.x >> 1;
    const int half  = blockIdx.x & 1;
    const int eb    = etile * TE;
    const int eg    = tid & 31;          // entity group: rows eg, eg+32
    const int bg    = (tid >> 5) * 4;    // first of 4 batch rows
    const int dbase = half * DQ;

    // staging decomposition (per thread):
    //   ent: 512 items, 2/thread: row = q>>3 (0..63), c4 = q&7
    //   rot: 256 items, 1/thread: row = tid>>3,       c4 = tid&7
    const int er0 = min(eb + (tid >> 3), E_TOT - 1);
    const int er1 = min(eb + ((tid + 256) >> 3), E_TOT - 1);
    const int ec0 = (tid & 7) << 2;
    const int rrow = tid >> 3;

    float4 pe_re[2], pe_im[2], p_rr, p_ri;

    auto load_chunk = [&](int dk) {
        const float* b0 = &ent[(size_t)er0 * (2 * DIMH)];
        const float* b1 = &ent[(size_t)er1 * (2 * DIMH)];
        pe_re[0] = *reinterpret_cast<const float4*>(b0 + dk + ec0);
        pe_im[0] = *reinterpret_cast<const float4*>(b0 + DIMH + dk + ec0);
        pe_re[1] = *reinterpret_cast<const float4*>(b1 + dk + ec0);
        pe_im[1] = *reinterpret_cast<const float4*>(b1 + DIMH + dk + ec0);
        p_rr = *reinterpret_cast<const float4*>(&rot[rrow * DIMH + dk + ec0]);
        p_ri = *reinterpret_cast<const float4*>(&rot[NB * DIMH + rrow * DIMH + dk + ec0]);
    };

    v2f acc[4][2];   // [batch j][entity k]
    #pragma unroll
    for (int j = 0; j < 4; ++j)
        #pragma unroll
        for (int k = 0; k < 2; ++k) { acc[j][k].x = 0.f; acc[j][k].y = 0.f; }

    load_chunk(dbase);

    for (int c = 0; c < NC; ++c) {
        // ---- store prefetched regs to LDS
        {
            int c4 = tid & 7;
            #pragma unroll
            for (int it = 0; it < 2; ++it) {
                int row = (tid + it * 256) >> 3;
                v4f lo, hi;
                lo.x = pe_re[it].x; lo.y = pe_re[it].y; lo.z = pe_im[it].x; lo.w = pe_im[it].y;
                hi.x = pe_re[it].z; hi.y = pe_re[it].w; hi.z = pe_im[it].z; hi.w = pe_im[it].w;
                s_e[row][2 * c4]     = lo;
                s_e[row][2 * c4 + 1] = hi;
            }
            v4f lo, hi;
            lo.x = p_rr.x; lo.y = p_rr.y; lo.z = p_ri.x; lo.w = p_ri.y;
            hi.x = p_rr.z; hi.y = p_rr.w; hi.z = p_ri.z; hi.w = p_ri.w;
            s_r[rrow][2 * c4]     = lo;
            s_r[rrow][2 * c4 + 1] = hi;
        }
        __syncthreads();

        // ---- issue next chunk's global loads (consumed after next barrier)
        if (c + 1 < NC) load_chunk(dbase + (c + 1) * DK);

        #pragma unroll 4
        for (int p = 0; p < DK / 2; ++p) {
            v4f r4[4], e4[2];
            #pragma unroll
            for (int j = 0; j < 4; ++j) r4[j] = s_r[bg + j][p];
            #pragma unroll
            for (int k = 0; k < 2; ++k) e4[k] = s_e[eg + 32 * k][p];
            #pragma unroll
            for (int j = 0; j < 4; ++j)
                #pragma unroll
                for (int k = 0; k < 2; ++k) {
                    v2f a = r4[j].xy - e4[k].xy;   // re diff (packed)
                    v2f b = r4[j].zw - e4[k].zw;   // im diff (packed)
                    v2f s = a * a + b * b;         // v_pk_mul + v_pk_fma
                    acc[j][k] += sqrt2(s);         // v_pk_add
                }
        }
        __syncthreads();
    }

    #pragma unroll
    for (int k = 0; k < 2; ++k) {
        int e = eb + eg + 32 * k;
        if (e < E_TOT) {
            #pragma unroll
            for (int j = 0; j < 4; ++j)
                atomicAdd(&out[(size_t)(bg + j) * E_TOT + e],
                          -(acc[j][k].x + acc[j][k].y));
        }
    }
}

extern "C" void kernel_launch(void* const* d_in, const int* in_sizes, int n_in,
                              void* d_out, int out_size, void* d_ws, size_t ws_size,
                              hipStream_t stream) {
    const float* head = (const float*)d_in[0];   // (32, 512)
    const float* rel  = (const float*)d_in[1];   // (32, 256)
    const float* ent  = (const float*)d_in[2];   // (43234, 512)
    float* rot = (float*)d_ws;                   // 2 * 32 * 256 floats = 64 KB

    int init_blocks = ((NB * E_TOT) / 4 + 255) / 256;   // 1352
    init_kernel<<<init_blocks, 256, 0, stream>>>((float*)d_out);
    rot_kernel<<<(NB * DIMH) / 256, 256, 0, stream>>>(head, rel, rot);

    int etiles = (E_TOT + TE - 1) / TE;          // 676
    dist_kernel<<<etiles * 2, 256, 0, stream>>>(ent, rot, (float*)d_out);
}